// Round 1
// baseline (9.262 us; speedup 1.0000x reference)
//
#include <hip/hip_runtime.h>

#define EPS_IOU 1e-7f

__global__ __launch_bounds__(1024) void IoULoss_75213467287779_kernel(
    const float4* __restrict__ pred, const float4* __restrict__ targ,
    float* __restrict__ out, int n) {
    const int tid = threadIdx.x;
    float sum = 0.0f;
    // n = 8192, blockDim = 1024 -> 8 iterations, fully unrollable
    #pragma unroll
    for (int k = 0; k < 8; ++k) {
        int i = tid + k * 1024;
        if (i < n) {
            float4 p = pred[i];   // cx, cy, w, h
            float4 t = targ[i];
            // corners exactly as reference: cx - w/2, cy - h/2, cx + w/2, cy + h/2
            float px1 = p.x - p.z * 0.5f, px2 = p.x + p.z * 0.5f;
            float py1 = p.y - p.w * 0.5f, py2 = p.y + p.w * 0.5f;
            float tx1 = t.x - t.z * 0.5f, tx2 = t.x + t.z * 0.5f;
            float ty1 = t.y - t.w * 0.5f, ty2 = t.y + t.w * 0.5f;

            float ix = fminf(px2, tx2) - fmaxf(px1, tx1);
            float iy = fminf(py2, ty2) - fmaxf(py1, ty1);
            float inter = fmaxf(ix, 0.0f) * fmaxf(iy, 0.0f);

            float a1 = (px2 - px1) * (py2 - py1);
            float a2 = (tx2 - tx1) * (ty2 - ty1);
            float uni = a1 + a2 - inter;
            sum += inter / (uni + EPS_IOU);
        }
    }

    // wave (64-lane) reduction
    #pragma unroll
    for (int off = 32; off > 0; off >>= 1)
        sum += __shfl_down(sum, off, 64);

    __shared__ float wsum[16];
    const int wid = tid >> 6;
    const int lane = tid & 63;
    if (lane == 0) wsum[wid] = sum;
    __syncthreads();

    if (wid == 0) {
        float s = (lane < 16) ? wsum[lane] : 0.0f;
        #pragma unroll
        for (int off = 8; off > 0; off >>= 1)
            s += __shfl_down(s, off, 64);
        if (lane == 0) out[0] = 1.0f - s / (float)n;
    }
}

extern "C" void kernel_launch(void* const* d_in, const int* in_sizes, int n_in,
                              void* d_out, int out_size, void* d_ws, size_t ws_size,
                              hipStream_t stream) {
    const float4* pred = (const float4*)d_in[0];
    const float4* targ = (const float4*)d_in[1];
    float* out = (float*)d_out;
    const int n = in_sizes[0] / 4;  // 8192 boxes
    IoULoss_75213467287779_kernel<<<1, 1024, 0, stream>>>(pred, targ, out, n);
}